// Round 3
// baseline (405.523 us; speedup 1.0000x reference)
//
#include <hip/hip_runtime.h>
#include <math.h>

#define SEQ_LEN   720
#define IN_LEN    360
#define PRED_LEN  336
#define CHANNELS  862
#define RANK      32
#define BATCH     256

// ws layout (float offsets)
#define WS_WP    0        // Wp  [360][32] = DCT^T@A folded, incl. 1/(360*sqrt2)
#define WS_VT    11520    // Vt  [336][32] = (B @ M_IDCT)^T
#define WS_CVEC  22272    // cvec[336]     = b @ M_IDCT

// ---------------- single prep kernel (89 blocks) -----------------------------
__global__ __launch_bounds__(256) void k_prep(const float* __restrict__ A,
                                              const float* __restrict__ B,
                                              const float* __restrict__ bias,
                                              float* __restrict__ Wp,
                                              float* __restrict__ Vt,
                                              float* __restrict__ cvec) {
    __shared__ float sbuf[IN_LEN * RANK];            // 46080 B
    int blk = blockIdx.x;
    if (blk < 45) {
        for (int i = threadIdx.x; i < IN_LEN * RANK; i += 256) sbuf[i] = A[i];
        __syncthreads();
        int idx = blk * 256 + threadIdx.x;           // 45*256 == 11520
        int n = idx >> 5, r = idx & 31;
        int step = 2 * n + 1, m = 0;                 // k*(2n+1) mod 1440
        float sum = 0.f;
        for (int k = 0; k < IN_LEN; ++k) {
            float coef = (k == 0) ? 0.05270462766947299f    // 1/sqrt(360)
                                  : 0.07453559924999299f;   // 2/sqrt(720)
            float d = coef * cospif((float)m * (1.0f / 720.0f));
            sum = fmaf(d, sbuf[k * RANK + r], sum);
            m += step; if (m >= 1440) m -= 1440;
        }
        Wp[idx] = sum * 0.0019641855032960957f;      // (1/sqrt2)/360
    } else if (blk < 87) {
        for (int i = threadIdx.x; i < PRED_LEN * RANK; i += 256) {
            int r = i / PRED_LEN, k = i - r * PRED_LEN;
            sbuf[k * RANK + r] = B[i];               // B transposed -> [k][r]
        }
        __syncthreads();
        int idx = (blk - 45) * 256 + threadIdx.x;    // 42*256 == 10752
        int n = idx >> 5, r = idx & 31;
        int step = 2 * n + 1, m = 0;                 // k*(2n+1) mod 1344
        float sum = 0.f;
        for (int k = 0; k < PRED_LEN; ++k) {
            float mk = cospif((float)m * (1.0f / 672.0f));
            if (k == 0) mk *= 0.5f;
            sum = fmaf(mk, sbuf[k * RANK + r], sum);
            m += step; if (m >= 1344) m -= 1344;
        }
        Vt[idx] = sum * (1.0f / 336.0f);
    } else {
        int n = (blk - 87) * 256 + threadIdx.x;
        if (n < PRED_LEN) {
            int step = 2 * n + 1, m = 0;
            float sum = 0.f;
            for (int k = 0; k < PRED_LEN; ++k) {
                float mk = cospif((float)m * (1.0f / 672.0f));
                if (k == 0) mk *= 0.5f;
                sum = fmaf(mk, bias[k], sum);
                m += step; if (m >= 1344) m -= 1344;
            }
            cvec[n] = sum * (1.0f / 336.0f);
        }
    }
}

// ---------------- fused main kernel ------------------------------------------
// 2 channels/thread. Weights read via wave-uniform global loads -> scalar pipe
// (s_load), consumed as the SGPR operand of v_fmac_f32. No LDS. x loads
// software-pipelined one iteration ahead.
__global__ __launch_bounds__(256, 2) void k_main(const float* __restrict__ x,
                                                 const float* __restrict__ A,
                                                 const float* __restrict__ Wp,
                                                 const float* __restrict__ Vt,
                                                 const float* __restrict__ cvec,
                                                 float* __restrict__ out) {
    const int tid = threadIdx.x;
    const int b = blockIdx.y;
    const int c0 = 2 * (blockIdx.x * 256 + tid);
    if (c0 >= CHANNELS) return;

    const float4* __restrict__ W4 = (const float4*)Wp;   // wave-uniform reads
    const float4* __restrict__ V4 = (const float4*)Vt;

    float acc0[RANK], acc1[RANK];
    #pragma unroll
    for (int r = 0; r < RANK; ++r) { acc0[r] = 0.f; acc1[r] = 0.f; }
    float S0 = 0.f, S1 = 0.f;

    const float* xp = x + (size_t)b * (SEQ_LEN * CHANNELS) + c0;

    // software-pipelined phase 1
    float2 na0 = *(const float2*)(xp);
    float2 na1 = *(const float2*)(xp + CHANNELS);

    for (int n = 0; n < IN_LEN; ++n) {
        float2 a0 = na0, a1 = na1;
        if (n < IN_LEN - 1) {
            na0 = *(const float2*)(xp + 2 * CHANNELS);
            na1 = *(const float2*)(xp + 3 * CHANNELS);
        }
        xp += 2 * CHANNELS;
        float p0 = a0.x + a1.x;
        float p1 = a0.y + a1.y;
        S0 += p0; S1 += p1;
        #pragma unroll
        for (int q = 0; q < 8; ++q) {
            float4 wv = W4[n * 8 + q];               // uniform -> s_load
            acc0[4*q+0] = fmaf(p0, wv.x, acc0[4*q+0]);
            acc1[4*q+0] = fmaf(p1, wv.x, acc1[4*q+0]);
            acc0[4*q+1] = fmaf(p0, wv.y, acc0[4*q+1]);
            acc1[4*q+1] = fmaf(p1, wv.y, acc1[4*q+1]);
            acc0[4*q+2] = fmaf(p0, wv.z, acc0[4*q+2]);
            acc1[4*q+2] = fmaf(p1, wv.z, acc1[4*q+2]);
            acc0[4*q+3] = fmaf(p0, wv.w, acc0[4*q+3]);
            acc1[4*q+3] = fmaf(p1, wv.w, acc1[4*q+3]);
        }
    }

    // finalize: csw[r] = A[0][r]/sqrt(720); t -= (S/360)*csw
    {
        float g0 = -S0 * (1.0f / 360.0f) * 0.037267799624996496f;
        float g1 = -S1 * (1.0f / 360.0f) * 0.037267799624996496f;
        #pragma unroll
        for (int q = 0; q < 8; ++q) {
            float4 a4 = ((const float4*)A)[q];       // A[0][0..31], uniform
            acc0[4*q+0] = fmaf(g0, a4.x, acc0[4*q+0]);
            acc1[4*q+0] = fmaf(g1, a4.x, acc1[4*q+0]);
            acc0[4*q+1] = fmaf(g0, a4.y, acc0[4*q+1]);
            acc1[4*q+1] = fmaf(g1, a4.y, acc1[4*q+1]);
            acc0[4*q+2] = fmaf(g0, a4.z, acc0[4*q+2]);
            acc1[4*q+2] = fmaf(g1, a4.z, acc1[4*q+2]);
            acc0[4*q+3] = fmaf(g0, a4.w, acc0[4*q+3]);
            acc1[4*q+3] = fmaf(g1, a4.w, acc1[4*q+3]);
        }
    }
    const float mean0 = S0 * (1.0f / 720.0f);
    const float mean1 = S1 * (1.0f / 720.0f);

    // phase 2: out[b][n][c] = t . Vt[n][:] + cvec[n] + mean
    float* op = out + (size_t)b * (PRED_LEN * CHANNELS) + c0;
    for (int n = 0; n < PRED_LEN; ++n) {
        float o0a = 0.f, o0b = 0.f, o0c = 0.f, o0d = 0.f;
        float o1a = 0.f, o1b = 0.f, o1c = 0.f, o1d = 0.f;
        #pragma unroll
        for (int q = 0; q < 8; ++q) {
            float4 vv = V4[n * 8 + q];               // uniform -> s_load
            o0a = fmaf(acc0[4*q+0], vv.x, o0a);
            o1a = fmaf(acc1[4*q+0], vv.x, o1a);
            o0b = fmaf(acc0[4*q+1], vv.y, o0b);
            o1b = fmaf(acc1[4*q+1], vv.y, o1b);
            o0c = fmaf(acc0[4*q+2], vv.z, o0c);
            o1c = fmaf(acc1[4*q+2], vv.z, o1c);
            o0d = fmaf(acc0[4*q+3], vv.w, o0d);
            o1d = fmaf(acc1[4*q+3], vv.w, o1d);
        }
        float cvn = cvec[n];                         // uniform
        float2 o;
        o.x = (o0a + o0b) + (o0c + o0d) + cvn + mean0;
        o.y = (o1a + o1b) + (o1c + o1d) + cvn + mean1;
        *(float2*)(op + n * CHANNELS) = o;
    }
}

// ---------------- launcher ---------------------------------------------------

extern "C" void kernel_launch(void* const* d_in, const int* in_sizes, int n_in,
                              void* d_out, int out_size, void* d_ws, size_t ws_size,
                              hipStream_t stream) {
    (void)in_sizes; (void)n_in; (void)out_size; (void)ws_size;
    const float* x    = (const float*)d_in[0];
    const float* A    = (const float*)d_in[1];
    const float* B    = (const float*)d_in[2];
    const float* bias = (const float*)d_in[3];
    float* out = (float*)d_out;
    float* ws  = (float*)d_ws;

    float* Wp   = ws + WS_WP;
    float* Vt   = ws + WS_VT;
    float* cvec = ws + WS_CVEC;

    k_prep<<<dim3(89), dim3(256), 0, stream>>>(A, B, bias, Wp, Vt, cvec);
    k_main<<<dim3(2, BATCH), dim3(256), 0, stream>>>(x, A, Wp, Vt, cvec, out);
}

// Round 4
// 342.955 us; speedup vs baseline: 1.1824x; 1.1824x over previous
//
#include <hip/hip_runtime.h>
#include <math.h>

#define SEQ_LEN   720
#define IN_LEN    360
#define PRED_LEN  336
#define CHANNELS  862
#define RANK      32
#define BATCH     256

// ws layout (float offsets)
#define WS_WP    0        // Wp  [360][32] = DCT^T@A folded, incl. 1/(360*sqrt2)
#define WS_VT    11520    // Vt  [336][32] = (B @ M_IDCT)^T
#define WS_CVEC  22272    // cvec[336]     = b @ M_IDCT

// ---------------- single prep kernel (89 blocks) -----------------------------
__global__ __launch_bounds__(256) void k_prep(const float* __restrict__ A,
                                              const float* __restrict__ B,
                                              const float* __restrict__ bias,
                                              float* __restrict__ Wp,
                                              float* __restrict__ Vt,
                                              float* __restrict__ cvec) {
    __shared__ float sbuf[IN_LEN * RANK];            // 46080 B
    int blk = blockIdx.x;
    if (blk < 45) {
        for (int i = threadIdx.x; i < IN_LEN * RANK; i += 256) sbuf[i] = A[i];
        __syncthreads();
        int idx = blk * 256 + threadIdx.x;           // 45*256 == 11520
        int n = idx >> 5, r = idx & 31;
        int step = 2 * n + 1, m = 0;                 // k*(2n+1) mod 1440
        float sum = 0.f;
        for (int k = 0; k < IN_LEN; ++k) {
            float coef = (k == 0) ? 0.05270462766947299f    // 1/sqrt(360)
                                  : 0.07453559924999299f;   // 2/sqrt(720)
            float d = coef * cospif((float)m * (1.0f / 720.0f));
            sum = fmaf(d, sbuf[k * RANK + r], sum);
            m += step; if (m >= 1440) m -= 1440;
        }
        Wp[idx] = sum * 0.0019641855032960957f;      // (1/sqrt2)/360
    } else if (blk < 87) {
        for (int i = threadIdx.x; i < PRED_LEN * RANK; i += 256) {
            int r = i / PRED_LEN, k = i - r * PRED_LEN;
            sbuf[k * RANK + r] = B[i];               // B transposed -> [k][r]
        }
        __syncthreads();
        int idx = (blk - 45) * 256 + threadIdx.x;    // 42*256 == 10752
        int n = idx >> 5, r = idx & 31;
        int step = 2 * n + 1, m = 0;                 // k*(2n+1) mod 1344
        float sum = 0.f;
        for (int k = 0; k < PRED_LEN; ++k) {
            float mk = cospif((float)m * (1.0f / 672.0f));
            if (k == 0) mk *= 0.5f;
            sum = fmaf(mk, sbuf[k * RANK + r], sum);
            m += step; if (m >= 1344) m -= 1344;
        }
        Vt[idx] = sum * (1.0f / 336.0f);
    } else {
        int n = (blk - 87) * 256 + threadIdx.x;
        if (n < PRED_LEN) {
            int step = 2 * n + 1, m = 0;
            float sum = 0.f;
            for (int k = 0; k < PRED_LEN; ++k) {
                float mk = cospif((float)m * (1.0f / 672.0f));
                if (k == 0) mk *= 0.5f;
                sum = fmaf(mk, bias[k], sum);
                m += step; if (m >= 1344) m -= 1344;
            }
            cvec[n] = sum * (1.0f / 336.0f);
        }
    }
}

// ---------------- fused main kernel ------------------------------------------
// 4 channels/thread, 128-thread blocks, grid (2, BATCH) -> 4 waves/CU.
// W/V staged in LDS (broadcast ds_read_b128). x loads: manual group-of-4
// software pipeline (16 float2 in flight). All global access float2 (8B-aligned
// always; 862 % 4 == 2 makes float4 misaligned on odd rows).
__global__ __launch_bounds__(128, 1) void k_main(const float* __restrict__ x,
                                                 const float* __restrict__ A,
                                                 const float* __restrict__ Wp,
                                                 const float* __restrict__ Vt,
                                                 const float* __restrict__ cvec,
                                                 float* __restrict__ out) {
    __shared__ float lds[IN_LEN * RANK];             // 46080 B (reused phase 2)
    const int tid = threadIdx.x;
    const int b = blockIdx.y;
    int c0 = 4 * (blockIdx.x * 128 + tid);
    if (c0 > CHANNELS - 4) c0 = CHANNELS - 4;        // 858: overlap-duplicate tail

    // ---- stage Wp ----
    {
        const float4* src = (const float4*)Wp;
        float4* dst = (float4*)lds;
        for (int i = tid; i < IN_LEN * RANK / 4; i += 128) dst[i] = src[i];
    }
    __syncthreads();

    float acc0[RANK], acc1[RANK], acc2[RANK], acc3[RANK];
    #pragma unroll
    for (int r = 0; r < RANK; ++r) { acc0[r]=0.f; acc1[r]=0.f; acc2[r]=0.f; acc3[r]=0.f; }
    float S0 = 0.f, S1 = 0.f, S2 = 0.f, S3 = 0.f;

    const float* xbase = x + (size_t)b * (SEQ_LEN * CHANNELS) + c0;
    #define LR2(row, half) (*(const float2*)(xbase + (size_t)(row) * CHANNELS + 2 * (half)))

    // group-of-4 pipeline: group g covers n=4g..4g+3 (rows 8g..8g+7)
    float2 cur[16], nxt[16];
    #pragma unroll
    for (int j = 0; j < 8; ++j) { cur[2*j] = LR2(j, 0); cur[2*j+1] = LR2(j, 1); }

    for (int g = 0; g < IN_LEN / 4; ++g) {
        const int nrb = (g < IN_LEN / 4 - 1) ? 8 * (g + 1) : 0;
        #pragma unroll
        for (int j = 0; j < 8; ++j) { nxt[2*j] = LR2(nrb + j, 0); nxt[2*j+1] = LR2(nrb + j, 1); }

        #pragma unroll
        for (int k = 0; k < 4; ++k) {                // n = 4g+k
            float2 e0 = cur[4*k+0], e1 = cur[4*k+1]; // row 8g+2k   (even)
            float2 o0 = cur[4*k+2], o1 = cur[4*k+3]; // row 8g+2k+1 (odd)
            float p0 = e0.x + o0.x, p1 = e0.y + o0.y;
            float p2 = e1.x + o1.x, p3 = e1.y + o1.y;
            S0 += p0; S1 += p1; S2 += p2; S3 += p3;
            const float4* wrow = (const float4*)lds + (4 * g + k) * 8;
            #pragma unroll
            for (int q = 0; q < 8; ++q) {
                float4 wv = wrow[q];
                acc0[4*q+0] = fmaf(p0, wv.x, acc0[4*q+0]);
                acc1[4*q+0] = fmaf(p1, wv.x, acc1[4*q+0]);
                acc2[4*q+0] = fmaf(p2, wv.x, acc2[4*q+0]);
                acc3[4*q+0] = fmaf(p3, wv.x, acc3[4*q+0]);
                acc0[4*q+1] = fmaf(p0, wv.y, acc0[4*q+1]);
                acc1[4*q+1] = fmaf(p1, wv.y, acc1[4*q+1]);
                acc2[4*q+1] = fmaf(p2, wv.y, acc2[4*q+1]);
                acc3[4*q+1] = fmaf(p3, wv.y, acc3[4*q+1]);
                acc0[4*q+2] = fmaf(p0, wv.z, acc0[4*q+2]);
                acc1[4*q+2] = fmaf(p1, wv.z, acc1[4*q+2]);
                acc2[4*q+2] = fmaf(p2, wv.z, acc2[4*q+2]);
                acc3[4*q+2] = fmaf(p3, wv.z, acc3[4*q+2]);
                acc0[4*q+3] = fmaf(p0, wv.w, acc0[4*q+3]);
                acc1[4*q+3] = fmaf(p1, wv.w, acc1[4*q+3]);
                acc2[4*q+3] = fmaf(p2, wv.w, acc2[4*q+3]);
                acc3[4*q+3] = fmaf(p3, wv.w, acc3[4*q+3]);
            }
        }
        #pragma unroll
        for (int j = 0; j < 16; ++j) cur[j] = nxt[j];
    }
    #undef LR2

    // finalize: csw[r] = A[0][r]/sqrt(720); t -= (S/360)*csw
    {
        const float k360 = (1.0f / 360.0f) * 0.037267799624996496f;
        float g0 = -S0 * k360, g1 = -S1 * k360, g2 = -S2 * k360, g3 = -S3 * k360;
        #pragma unroll
        for (int q = 0; q < 8; ++q) {
            float4 a4 = ((const float4*)A)[q];       // A[0][0..31], uniform L2-hot
            acc0[4*q+0] = fmaf(g0, a4.x, acc0[4*q+0]);
            acc1[4*q+0] = fmaf(g1, a4.x, acc1[4*q+0]);
            acc2[4*q+0] = fmaf(g2, a4.x, acc2[4*q+0]);
            acc3[4*q+0] = fmaf(g3, a4.x, acc3[4*q+0]);
            acc0[4*q+1] = fmaf(g0, a4.y, acc0[4*q+1]);
            acc1[4*q+1] = fmaf(g1, a4.y, acc1[4*q+1]);
            acc2[4*q+1] = fmaf(g2, a4.y, acc2[4*q+1]);
            acc3[4*q+1] = fmaf(g3, a4.y, acc3[4*q+1]);
            acc0[4*q+2] = fmaf(g0, a4.z, acc0[4*q+2]);
            acc1[4*q+2] = fmaf(g1, a4.z, acc1[4*q+2]);
            acc2[4*q+2] = fmaf(g2, a4.z, acc2[4*q+2]);
            acc3[4*q+2] = fmaf(g3, a4.z, acc3[4*q+2]);
            acc0[4*q+3] = fmaf(g0, a4.w, acc0[4*q+3]);
            acc1[4*q+3] = fmaf(g1, a4.w, acc1[4*q+3]);
            acc2[4*q+3] = fmaf(g2, a4.w, acc2[4*q+3]);
            acc3[4*q+3] = fmaf(g3, a4.w, acc3[4*q+3]);
        }
    }
    const float mean0 = S0 * (1.0f / 720.0f);
    const float mean1 = S1 * (1.0f / 720.0f);
    const float mean2 = S2 * (1.0f / 720.0f);
    const float mean3 = S3 * (1.0f / 720.0f);

    __syncthreads();                                 // phase-1 LDS reads done

    // ---- re-stage LDS with Vt + cvec ----
    {
        const float4* src = (const float4*)Vt;
        float4* dst = (float4*)lds;
        for (int i = tid; i < PRED_LEN * RANK / 4; i += 128) dst[i] = src[i];
        const float4* src2 = (const float4*)cvec;
        float4* dst2 = (float4*)(lds + PRED_LEN * RANK);
        for (int i = tid; i < PRED_LEN / 4; i += 128) dst2[i] = src2[i];
    }
    __syncthreads();

    // phase 2: out[b][n][c0..c0+3] = t . Vt[n][:] + cvec[n] + mean
    float* op = out + (size_t)b * (PRED_LEN * CHANNELS) + c0;
    for (int n = 0; n < PRED_LEN; ++n) {
        const float4* vrow = (const float4*)lds + n * 8;
        float o0a=0.f,o0b=0.f,o0c=0.f,o0d=0.f;
        float o1a=0.f,o1b=0.f,o1c=0.f,o1d=0.f;
        float o2a=0.f,o2b=0.f,o2c=0.f,o2d=0.f;
        float o3a=0.f,o3b=0.f,o3c=0.f,o3d=0.f;
        #pragma unroll
        for (int q = 0; q < 8; ++q) {
            float4 vv = vrow[q];
            o0a = fmaf(acc0[4*q+0], vv.x, o0a);
            o1a = fmaf(acc1[4*q+0], vv.x, o1a);
            o2a = fmaf(acc2[4*q+0], vv.x, o2a);
            o3a = fmaf(acc3[4*q+0], vv.x, o3a);
            o0b = fmaf(acc0[4*q+1], vv.y, o0b);
            o1b = fmaf(acc1[4*q+1], vv.y, o1b);
            o2b = fmaf(acc2[4*q+1], vv.y, o2b);
            o3b = fmaf(acc3[4*q+1], vv.y, o3b);
            o0c = fmaf(acc0[4*q+2], vv.z, o0c);
            o1c = fmaf(acc1[4*q+2], vv.z, o1c);
            o2c = fmaf(acc2[4*q+2], vv.z, o2c);
            o3c = fmaf(acc3[4*q+2], vv.z, o3c);
            o0d = fmaf(acc0[4*q+3], vv.w, o0d);
            o1d = fmaf(acc1[4*q+3], vv.w, o1d);
            o2d = fmaf(acc2[4*q+3], vv.w, o2d);
            o3d = fmaf(acc3[4*q+3], vv.w, o3d);
        }
        float cvn = lds[PRED_LEN * RANK + n];
        float2 w0, w1;
        w0.x = (o0a + o0b) + (o0c + o0d) + cvn + mean0;
        w0.y = (o1a + o1b) + (o1c + o1d) + cvn + mean1;
        w1.x = (o2a + o2b) + (o2c + o2d) + cvn + mean2;
        w1.y = (o3a + o3b) + (o3c + o3d) + cvn + mean3;
        *(float2*)(op + (size_t)n * CHANNELS)     = w0;
        *(float2*)(op + (size_t)n * CHANNELS + 2) = w1;
    }
}

// ---------------- launcher ---------------------------------------------------

extern "C" void kernel_launch(void* const* d_in, const int* in_sizes, int n_in,
                              void* d_out, int out_size, void* d_ws, size_t ws_size,
                              hipStream_t stream) {
    (void)in_sizes; (void)n_in; (void)out_size; (void)ws_size;
    const float* x    = (const float*)d_in[0];
    const float* A    = (const float*)d_in[1];
    const float* B    = (const float*)d_in[2];
    const float* bias = (const float*)d_in[3];
    float* out = (float*)d_out;
    float* ws  = (float*)d_ws;

    float* Wp   = ws + WS_WP;
    float* Vt   = ws + WS_VT;
    float* cvec = ws + WS_CVEC;

    k_prep<<<dim3(89), dim3(256), 0, stream>>>(A, B, bias, Wp, Vt, cvec);
    k_main<<<dim3(2, BATCH), dim3(128), 0, stream>>>(x, A, Wp, Vt, cvec, out);
}